// Round 13
// baseline (106.109 us; speedup 1.0000x reference)
//
#include <hip/hip_runtime.h>

// PrimalDualNetwork: 10-iter Chambolle-Pock ROF on 2048x2048 fp32.
// R20 = R19b + own-qv kept in register (qvr). R19b post-mortem: issue
// diet flat (46.7us); model says LDS pipe (~10 issues/unit-iter,
// ~30-32us busy) >= VALU (~28us); makespan 46.7 = max(pipes) + stalls.
// Barriers irreducible (both protect true cross-thread deps). Cut LDS:
//  - primal's own-qv LDS read deleted; value carried in qvr[NPASS]
//    (+4 VGPR named state -> 28 at the hard 32 cap; mild spill OK per
//    R10 precedent ~30MB on the idle VMEM pipe, fatal only at R14's
//    ~20-reg overflow). LDS issues 10 -> 9 per unit-iter.
//  - qvr never stale: cone deactivation is monotone; cross-thread qvu
//    still via LDS (unchanged semantics).
// Tripwires: WRITE > 50 MB => spill too big, revert; dur >= 46.5 with
// clean WRITE => 2-barrier structure ceiling confirmed.
// absmax expected exactly 0.00390625 (zero numeric change).

namespace {
constexpr int M = 2048, N = 2048;
constexpr float SIGMA     = 1.0f / (7.0f * 0.01f);
constexpr float TAUIS     = 0.01f * (7.0f * 0.01f);  // tau/sigma
constexpr float LT        = 4.0f * 0.01f;
constexpr float INV_DEN   = 1.0f / (1.0f + 4.0f * 0.01f);
constexpr float TAUIS_ID  = TAUIS * INV_DEN;
constexpr float LT_ID     = LT * INV_DEN;
constexpr int TW = 64, TH = 64;     // output tile
constexpr int PC = 88;              // plane cols (12 + 64 + 12)
constexpr int PR = 84;              // plane rows (10 + 64 + 10)
constexpr int UPR = 22;             // h4 units per row == PC/4
constexpr int PROC = 83;            // rows 0..82 processed (83 read-only)
constexpr int NU = PROC * UPR;      // 1826
constexpr int NT = 1024;            // 16 waves
constexpr int NPASS = 2;            // 2*1024 >= NU (and >= PR*UPR=1848)
constexpr int GY = M / TH;          // 32  (exact: no partial tiles)
} // namespace

typedef _Float16 h4 __attribute__((ext_vector_type(4)));
typedef float    f2 __attribute__((ext_vector_type(2)));
typedef unsigned uint32;

__device__ inline h4 h4splat(float v) {
    _Float16 s = (_Float16)v;
    return (h4){s, s, s, s};
}
__device__ inline int imax(int a, int b) { return a > b ? a : b; }
__device__ inline uint32 abit(uint32 hi, uint32 lo) {
    return __builtin_amdgcn_alignbit(hi, lo, 16);
}
__device__ inline h4 clamp1(h4 v) {
    return __builtin_elementwise_min(
               __builtin_elementwise_max(v, h4splat(-1.f)), h4splat(1.f));
}
// packed f32->f16 (RTZ); builtin returns __fp16x2 -> pass through uint32
__device__ inline uint32 pkrtz(float a, float b) {
    return __builtin_bit_cast(uint32, __builtin_amdgcn_cvt_pkrtz(a, b));
}

__global__ __launch_bounds__(NT, 8) void pd_fused(
    const float* __restrict__ img, float* __restrict__ out,
    const float* __restrict__ w1p, const float* __restrict__ w2p)
{
    __shared__ __align__(16) _Float16 sXT16[PR * PC];   // 14784 B (xt, fp16)
    __shared__ __align__(16) _Float16 sQV[PR * PC];     // 14784 B
    __shared__ __align__(16) _Float16 sCI[PR * PC];     // 14784 B (LT_ID*img)
    __shared__ __align__(16) _Float16 sSW[2 * PR * PC]; // 29568 B (swh|swv interleaved per unit)
    __shared__ __align__(16) _Float16 sQH3[1840];       //  3680 B (qH[3]/unit)

    const int tid  = threadIdx.x;
    const int c0 = blockIdx.x * TW, r0 = blockIdx.y * TH;
    const int gr0 = r0 - 10, gc0 = c0 - 12;
    const float w1 = w1p[0], w2 = w2p[0];

    // cone deactivation threshold per pass (active iff rem >= d)
    int dth_[NPASS];
    #pragma unroll
    for (int p = 0; p < NPASS; ++p) {
        int u = tid + p * NT;
        int li = u / UPR, lc = (u - li * UPR) * 4;
        int d = imax(imax(9 - li, li - (TH + 9)), imax(8 - lc, lc - 75));
        d = imax(d, 0);
        if (u >= NU) d = 100;
        dth_[p] = d;
    }

    // ---- stage img -> sXT16 (fp16; 0 outside image) ----
    #pragma unroll
    for (int p = 0; p < NPASS; ++p) {
        int su = tid + p * NT;
        if (su < PR * UPR) {
            int li = su / UPR, uj = su - li * UPR;
            int gi = gr0 + li, gj = gc0 + uj * 4;
            float4 v = make_float4(0.f, 0.f, 0.f, 0.f);
            if ((unsigned)gi < (unsigned)M && (unsigned)gj <= (unsigned)(N - 4))
                v = *(const float4*)&img[(size_t)gi * N + gj];
            h4 h; h[0] = (_Float16)v.x; h[1] = (_Float16)v.y;
                  h[2] = (_Float16)v.z; h[3] = (_Float16)v.w;
            *(h4*)&sXT16[su * 4] = h;
        }
    }
    __syncthreads();

    // register state (28 named at 32 cap): x fp32 pairs, xt/y/q/qv fp16
    f2 xr2[NPASS][2];
    h4 xt16[NPASS], yh[NPASS], yv[NPASS], qH[NPASS], qvr[NPASS];

    // ---- init (== dual(0)): sigma*w -> sSW, ci -> sCI, y0, q0 ----
    #pragma unroll
    for (int p = 0; p < NPASS; ++p) {
        int u = tid + p * NT;
        if (u < NU) {
            int bF = u * 4;
            int li = u / UPR;
            int gi = gr0 + li, gjb = gc0 + (u - li * UPR) * 4;
            h4 c16 = *(const h4*)&sXT16[bF];
            uint32 rrp = *(const uint32*)&sXT16[bF + 4];
            h4 dn = *(const h4*)&sXT16[bF + PC];
            uint2 xu = __builtin_bit_cast(uint2, c16);
            h4 xsh = __builtin_bit_cast(h4,
                         make_uint2(abit(xu.y, xu.x), abit(rrp, xu.y)));
            bool rok = (unsigned)gi < (unsigned)M;
            bool vok = rok && (gi < M - 1);
            h4 qv, swhv, swvv, civ;
            #pragma unroll
            for (int l = 0; l < 4; ++l) {
                int gj = gjb + l;
                bool cok = (unsigned)gj < (unsigned)N;
                bool hok = rok && cok && (gj < N - 1);
                bool vk  = vok && cok;
                float xf  = (float)c16[l];
                float ghf = hok ? (float)xsh[l] - xf : 0.f;
                float gvf = vk  ? (float)dn[l]  - xf : 0.f;
                float wh = fmaf(w2, __expf(-fabsf(ghf)), w1);
                float wv = fmaf(w2, __expf(-fabsf(gvf)), w1);
                float y0h = fminf(fmaxf(ghf * fmaf(SIGMA, wh, 1.f), -1.f), 1.f);
                float y0v = fminf(fmaxf(gvf * fmaf(SIGMA, wv, 1.f), -1.f), 1.f);
                float sh = hok ? SIGMA * wh : 0.f;
                float sv = vk  ? SIGMA * wv : 0.f;
                yh[p][l]   = (_Float16)y0h;  yv[p][l] = (_Float16)y0v;
                swhv[l]    = (_Float16)sh;   swvv[l]  = (_Float16)sv;
                qH[p][l]   = (_Float16)(sh * y0h);
                qv[l]      = (_Float16)(sv * y0v);
                civ[l]     = (_Float16)(LT_ID * xf);
                xr2[p][l >> 1][l & 1] = xf;
            }
            xt16[p] = c16;
            qvr[p]  = qv;
            *(h4*)&sSW[bF * 2]     = swhv;   // unit u: halves [8u, 8u+4)
            *(h4*)&sSW[bF * 2 + 4] = swvv;   //          halves [8u+4, 8u+8)
            *(h4*)&sCI[bF]  = civ;
            *(h4*)&sQV[bF]  = qv;
            sQH3[u] = qH[p][3];
        }
    }
    __syncthreads();

    // ---- dual(t>=1): y = clamp(y + sw*grad16(xt)); q = sw*y
    //      sw via ONE b128 read of the interleaved plane ----
    auto dual = [&](int rem) {
        #pragma unroll
        for (int p = 0; p < NPASS; ++p) {
            if (rem >= dth_[p]) {
                int bF = (tid + p * NT) * 4;
                uint32 rrp = *(const uint32*)&sXT16[bF + 4];
                h4 dn  = *(const h4*)&sXT16[bF + PC];
                uint4 swp = *(const uint4*)&sSW[bF * 2];     // b128
                h4 swh = __builtin_bit_cast(h4, make_uint2(swp.x, swp.y));
                h4 swv = __builtin_bit_cast(h4, make_uint2(swp.z, swp.w));
                uint2 xu = __builtin_bit_cast(uint2, xt16[p]);
                h4 xsh = __builtin_bit_cast(h4,
                             make_uint2(abit(xu.y, xu.x), abit(rrp, xu.y)));
                h4 ghh = xsh - xt16[p];              // v_pk_sub_f16
                h4 gvh = dn  - xt16[p];
                h4 nh = clamp1(yh[p] + swh * ghh);   // sw=0 masks borders
                h4 nv = clamp1(yv[p] + swv * gvh);
                yh[p] = nh; yv[p] = nv;
                h4 qh = swh * nh;                    // q = sigma*w*y
                h4 qv = swv * nv;
                qH[p] = qh; qvr[p] = qv;
                *(h4*)&sQV[bF] = qv;
                sQH3[bF >> 2] = qh[3];
            }
        }
    };

    // ---- primal: s16 = TAUIS_ID*dvg + ci (packed f16);
    //      xn = fma(INV_DEN, xo, cvt(s16)); xt = 1.5xn - 0.5xo;
    //      own qv from register (qvr); repack via v_cvt_pkrtz.
    //      last: fp32 store, skip LDS. ----
    const f2 kID  = {INV_DEN,  INV_DEN};
    const f2 k15  = {1.5f, 1.5f};
    const f2 km05 = {-0.5f, -0.5f};
    const h4 kTS16 = h4splat(TAUIS_ID);
    auto primal = [&](int rem, bool last) {
        #pragma unroll
        for (int p = 0; p < NPASS; ++p) {
            if (rem >= dth_[p]) {
                int u = tid + p * NT, bF = u * 4;
                int bu = (bF >= UPR * 4) ? bF - PC : bF;  // row-0 junk tolerated
                h4 qvu = *(const h4*)&sQV[bu];
                h4 civ = *(const h4*)&sCI[bF];
                uint32 qhl = *(const unsigned short*)&sQH3[imax(u - 1, 0)];
                uint2 qu = __builtin_bit_cast(uint2, qH[p]);
                h4 qsh = __builtin_bit_cast(h4,
                             make_uint2(abit(qu.x, qhl << 16), abit(qu.y, qu.x)));
                h4 dvg = (qH[p] - qsh) + (qvr[p] - qvu);  // v_pk_sub/add_f16
                h4 s16 = kTS16 * dvg + civ;               // packed f16 fma
                f2 s0 = {(float)s16[0], (float)s16[1]};
                f2 s1 = {(float)s16[2], (float)s16[3]};
                f2 xo0 = xr2[p][0], xo1 = xr2[p][1];
                f2 xn0 = __builtin_elementwise_fma(kID, xo0, s0);
                f2 xn1 = __builtin_elementwise_fma(kID, xo1, s1);
                xr2[p][0] = xn0; xr2[p][1] = xn1;
                f2 xt0 = __builtin_elementwise_fma(k15, xn0, xo0 * km05);
                f2 xt1 = __builtin_elementwise_fma(k15, xn1, xo1 * km05);
                if (!last) {
                    h4 nx = __builtin_bit_cast(h4,
                        make_uint2(pkrtz(xt0[0], xt0[1]),
                                   pkrtz(xt1[0], xt1[1])));
                    xt16[p] = nx;
                    *(h4*)&sXT16[bF] = nx;
                } else {
                    int li = u / UPR, uj = u - li * UPR;
                    int gi = gr0 + li;
                    if (li >= 10 && uj >= 3 && uj <= 18 && gi < M) {
                        *(float4*)&out[(size_t)gi * N + (gc0 + uj * 4)] =
                            make_float4(xt0[0], xt0[1], xt1[0], xt1[1]);
                    }
                }
            }
        }
    };

    primal(9, false);          // t=0 (dual(0) fused into init)
    __syncthreads();
    #pragma unroll 1
    for (int t = 1; t < 10; ++t) {
        int rem = 9 - t;
        dual(rem);
        __syncthreads();
        primal(rem, t == 9);
        __syncthreads();
    }
}

extern "C" void kernel_launch(void* const* d_in, const int* in_sizes, int n_in,
                              void* d_out, int out_size, void* d_ws, size_t ws_size,
                              hipStream_t stream)
{
    const float* img = (const float*)d_in[0];
    const float* w1  = (const float*)d_in[1];
    const float* w2  = (const float*)d_in[2];
    float* out = (float*)d_out;

    dim3 grid(N / TW, GY);   // 32 x 32 = 1024 blocks = 2/CU x 2 rounds
    pd_fused<<<grid, NT, 0, stream>>>(img, out, w1, w2);
}